// Round 1
// baseline (291.997 us; speedup 1.0000x reference)
//
#include <hip/hip_runtime.h>

#define DIM   64
#define KCB   1024
#define RPB   256          // rows per block (unchanged)
#define NTHR  512          // 8 waves/block now
#define SMEM_WORDS 20480   // 16384 x + 2048 dtab + 2048 ktab (codes folded into ktab)
#define SMEM_BYTES (SMEM_WORDS * 4)

// ws layout (floats): ws[0] = loss accumulator; ws[256..1279] = csq[k]

__global__ void vq_prep(const float* __restrict__ cb, float* __restrict__ ws) {
    int k = blockIdx.x * blockDim.x + threadIdx.x;
    if (k < KCB) {
        const float* e = cb + (k << 6);
        {
            #pragma clang fp contract(off)
            float racc[8];
            #pragma unroll
            for (int j = 0; j < 8; ++j) racc[j] = e[j] * e[j];
            #pragma unroll
            for (int t = 1; t < 8; ++t) {
                #pragma unroll
                for (int j = 0; j < 8; ++j) racc[j] += e[8 * t + j] * e[8 * t + j];
            }
            ws[256 + k] = ((racc[0] + racc[1]) + (racc[2] + racc[3]))
                        + ((racc[4] + racc[5]) + (racc[6] + racc[7]));
        }
    }
    if (k == 0) ws[0] = 0.0f;
}

// 2D register-tiled VQ kernel, 8-wave variant.
//  - 256 rows/block staged in LDS (XOR-swizzled: word = row*64 + ((cj^(row&15))*4)).
//  - wave w scans entry EIGHTH [w*128, w*128+128); e addresses are uniform
//    (readfirstlane) -> scalar s_load_dwordx4 broadcast.
//  - each lane: 4 rows x 16 entries of accumulators (same amortization as the
//    4-wave version; only the per-wave entry span halved).
//  - LDS cut to exactly 80 KB so 2 blocks/CU still fit -> 16 waves/CU
//    (4/SIMD, was 2/SIMD): fills the ~34% idle issue slots seen at
//    VALUBusy=66% / Occupancy=19.9%.
//  - per-dot j-chain strictly sequential (bit-identical to the passing kernel);
//    argmin = ascending strict-<, eighths lex-min combined ascending.
__global__ __launch_bounds__(512, 4) void vq_main(
        const float* __restrict__ in,
        const float* __restrict__ cb,
        const float* __restrict__ csq,      // = ws + 256
        float* __restrict__ codes_f,
        float* __restrict__ out,
        float* __restrict__ loss_acc)       // = ws + 0
{
    extern __shared__ float smem[];
    float* xs    = smem;                    // 16384 words, swizzled x
    float* dtab  = smem + 16384;            // 2048: per-row per-eighth best d
    int*   ktab  = (int*)(smem + 18432);    // 2048: per-row per-eighth best k

    const int tid  = threadIdx.x;
    const int lane = tid & 63;
    const int q    = __builtin_amdgcn_readfirstlane(tid >> 6);   // entry eighth 0..7
    const size_t rowBase = (size_t)blockIdx.x * RPB;

    // ---- stage x, swizzled ----
    {
        const float4* gx = (const float4*)(in + rowBase * DIM);
        #pragma unroll
        for (int i = 0; i < 8; ++i) {
            int idx = i * 512 + tid;
            int row = idx >> 4, cj = idx & 15;
            float4 v = gx[idx];
            *(float4*)(xs + row * 64 + ((cj ^ (row & 15)) << 2)) = v;
        }
    }
    __syncthreads();

    // ---- A = ||x||^2 for my 4 rows (exact numpy pairwise-8 order) ----
    float A[4];
    #pragma unroll
    for (int ri = 0; ri < 4; ++ri) {
        const int row = lane + (ri << 6);       // row&15 == lane&15
        float xv[64];
        #pragma unroll
        for (int cj = 0; cj < 16; ++cj) {
            float4 v = *(const float4*)(xs + row * 64 + ((cj ^ (lane & 15)) << 2));
            xv[cj*4+0]=v.x; xv[cj*4+1]=v.y; xv[cj*4+2]=v.z; xv[cj*4+3]=v.w;
        }
        {
            #pragma clang fp contract(off)
            float racc[8];
            #pragma unroll
            for (int j = 0; j < 8; ++j) racc[j] = xv[j] * xv[j];
            #pragma unroll
            for (int t = 1; t < 8; ++t) {
                #pragma unroll
                for (int j = 0; j < 8; ++j) racc[j] += xv[8*t+j] * xv[8*t+j];
            }
            A[ri] = ((racc[0] + racc[1]) + (racc[2] + racc[3]))
                  + ((racc[4] + racc[5]) + (racc[6] + racc[7]));
        }
    }

    // ---- main scan: my eighth's 128 entries, 16 at a time ----
    const float* cbq   = cb  + ((size_t)q << 13);   // q*128 entries * 64
    const float* csq_q = csq + (q << 7);
    float dmin[4] = {3.402823466e38f, 3.402823466e38f, 3.402823466e38f, 3.402823466e38f};
    int   kmin[4] = {0, 0, 0, 0};
    const int xb = lane * 64;

    #pragma unroll 1
    for (int ke = 0; ke < 128; ke += 16) {
        float m[4][16];
        #pragma unroll
        for (int ri = 0; ri < 4; ++ri)
            #pragma unroll
            for (int e = 0; e < 16; ++e) m[ri][e] = 0.0f;

        #pragma unroll 1
        for (int jb = 0; jb < 64; jb += 4) {
            const int slot4 = ((jb >> 2) ^ (lane & 15)) << 2;
            float4 a0 = *(const float4*)(xs + xb +         slot4);
            float4 a1 = *(const float4*)(xs + xb +  4096 + slot4);
            float4 a2 = *(const float4*)(xs + xb +  8192 + slot4);
            float4 a3 = *(const float4*)(xs + xb + 12288 + slot4);
            #pragma unroll
            for (int e = 0; e < 16; ++e) {
                float4 ev = *(const float4*)(cbq + ((ke + e) << 6) + jb); // uniform -> s_load
                m[0][e] = __builtin_fmaf(a0.x, ev.x, m[0][e]);
                m[0][e] = __builtin_fmaf(a0.y, ev.y, m[0][e]);
                m[0][e] = __builtin_fmaf(a0.z, ev.z, m[0][e]);
                m[0][e] = __builtin_fmaf(a0.w, ev.w, m[0][e]);
                m[1][e] = __builtin_fmaf(a1.x, ev.x, m[1][e]);
                m[1][e] = __builtin_fmaf(a1.y, ev.y, m[1][e]);
                m[1][e] = __builtin_fmaf(a1.z, ev.z, m[1][e]);
                m[1][e] = __builtin_fmaf(a1.w, ev.w, m[1][e]);
                m[2][e] = __builtin_fmaf(a2.x, ev.x, m[2][e]);
                m[2][e] = __builtin_fmaf(a2.y, ev.y, m[2][e]);
                m[2][e] = __builtin_fmaf(a2.z, ev.z, m[2][e]);
                m[2][e] = __builtin_fmaf(a2.w, ev.w, m[2][e]);
                m[3][e] = __builtin_fmaf(a3.x, ev.x, m[3][e]);
                m[3][e] = __builtin_fmaf(a3.y, ev.y, m[3][e]);
                m[3][e] = __builtin_fmaf(a3.z, ev.z, m[3][e]);
                m[3][e] = __builtin_fmaf(a3.w, ev.w, m[3][e]);
            }
        }

        #pragma unroll
        for (int e = 0; e < 16; ++e) {
            float cse = csq_q[ke + e];              // uniform
            int gk = (q << 7) + ke + e;
            #pragma unroll
            for (int ri = 0; ri < 4; ++ri) {
                float d;
                {
                    #pragma clang fp contract(off)
                    d = (A[ri] - 2.0f * m[ri][e]) + cse;
                }
                if (d < dmin[ri]) { dmin[ri] = d; kmin[ri] = gk; }  // ascending, strict <
            }
        }
    }

    // ---- cross-eighth lex-min combine ----
    #pragma unroll
    for (int ri = 0; ri < 4; ++ri) {
        int row = lane + (ri << 6);
        dtab[row * 8 + q] = dmin[ri];
        ktab[row * 8 + q] = kmin[ri];
    }
    __syncthreads();

    float db = 0.0f;
    if (tid < RPB) {
        db = dtab[tid * 8];
        int kb = ktab[tid * 8];
        #pragma unroll
        for (int qq = 1; qq < 8; ++qq) {    // ascending eighths, strict <
            float dq = dtab[tid * 8 + qq];
            int   kq = ktab[tid * 8 + qq];
            if (dq < db) { db = dq; kb = kq; }
        }
        ktab[tid * 8] = kb;                 // publish code (own slot, read already done)
        codes_f[rowBase + tid] = (float)kb;
    }
    __syncthreads();

    // ---- fused straight-through write: st = x + (q - x) ----
    {
        float4* gout = (float4*)(out + rowBase * DIM);
        #pragma unroll
        for (int i = 0; i < 8; ++i) {
            int idx = i * 512 + tid;
            int row = idx >> 4, cj = idx & 15;
            int code = ktab[row * 8];
            float4 qv = *(const float4*)(cb + ((size_t)code << 6) + (cj << 2));
            float4 xv = *(const float4*)(xs + row * 64 + ((cj ^ (row & 15)) << 2));
            float4 st;
            {
                #pragma clang fp contract(off)
                st.x = xv.x + (qv.x - xv.x);
                st.y = xv.y + (qv.y - xv.y);
                st.z = xv.z + (qv.z - xv.z);
                st.w = xv.w + (qv.w - xv.w);
            }
            gout[idx] = st;
        }
    }

    // ---- loss partial (dtab reused as reduction tree; same 256-leaf order) ----
    if (tid < RPB) dtab[tid] = db;
    __syncthreads();
    #pragma unroll
    for (int s = 128; s > 0; s >>= 1) {
        if (tid < s) dtab[tid] += dtab[tid + s];
        __syncthreads();
    }
    if (tid == 0) atomicAdd(loss_acc, dtab[0]);
}

__global__ void vq_final(const float* __restrict__ ws, float* __restrict__ loss_out) {
    // loss = codebook_loss + BETA*commitment = 1.25 * mean((x-q)^2)
    loss_out[0] = 1.25f * ws[0] / 8388608.0f;
}

extern "C" void kernel_launch(void* const* d_in, const int* in_sizes, int n_in,
                              void* d_out, int out_size, void* d_ws, size_t ws_size,
                              hipStream_t stream) {
    const float* in = (const float*)d_in[0];   // (32,4096,64) fp32
    const float* cb = (const float*)d_in[1];   // (1024,64)    fp32
    float* out     = (float*)d_out;
    float* codes_f = out + 8388608;
    float* loss_p  = out + 8519680;
    float* ws      = (float*)d_ws;

    hipFuncSetAttribute((const void*)vq_main,
                        hipFuncAttributeMaxDynamicSharedMemorySize, SMEM_BYTES);

    vq_prep <<<4,   256, 0,          stream>>>(cb, ws);
    vq_main <<<512, 512, SMEM_BYTES, stream>>>(in, cb, ws + 256, codes_f, out, ws);
    vq_final<<<1,   1,   0,          stream>>>(ws, loss_p);
}

// Round 2
// 266.358 us; speedup vs baseline: 1.0963x; 1.0963x over previous
//
#include <hip/hip_runtime.h>

#define DIM   64
#define KCB   1024
#define RPB   256
#define QCAP  1536

// ws layout (floats): ws[0] = loss acc; ws[256..1279] = csq[k];
//                     ws[2048..] = cb_hi bf16 [1024][64] (32768 float slots)
#define WS_NEED_BYTES ((2048 + 32768) * 4)

typedef __attribute__((ext_vector_type(8))) short short8;
typedef __attribute__((ext_vector_type(4))) float f32x4;

__device__ __forceinline__ unsigned short f2bf(float f) {
    union { float f; unsigned u; } v; v.f = f;
    unsigned u = v.u;
    return (unsigned short)((u + 0x7FFFu + ((u >> 16) & 1u)) >> 16);  // RNE
}

__global__ void vq_prep(const float* __restrict__ cb, float* __restrict__ ws, int do_bf) {
    int k = blockIdx.x * blockDim.x + threadIdx.x;
    if (k < KCB) {
        const float* e = cb + (k << 6);
        {
            #pragma clang fp contract(off)
            float racc[8];
            #pragma unroll
            for (int j = 0; j < 8; ++j) racc[j] = e[j] * e[j];
            #pragma unroll
            for (int t = 1; t < 8; ++t) {
                #pragma unroll
                for (int j = 0; j < 8; ++j) racc[j] += e[8 * t + j] * e[8 * t + j];
            }
            ws[256 + k] = ((racc[0] + racc[1]) + (racc[2] + racc[3]))
                        + ((racc[4] + racc[5]) + (racc[6] + racc[7]));
        }
        if (do_bf) {
            unsigned short* cbh = (unsigned short*)(ws + 2048);
            #pragma unroll
            for (int j = 0; j < 64; ++j) cbh[(k << 6) + j] = f2bf(e[j]);
        }
    }
    if (k == 0) ws[0] = 0.0f;
}

// MFMA-filtered VQ:
//  - per block: 256 rows, 4 waves; wave w owns rows [w*64, w*64+64).
//  - A-frags (x rows, bf16-hi) persist in regs: af[mt][h], rows wrow+mt*16+(lane&15),
//    dims h*32+(lane>>4)*8 .. +8  (16x16x32 bf16 A-layout: row=lane&15, k=(lane>>4)*8+j).
//  - acc init = -csq[n]/2, so score = csq - 2*dot = -2*acc -> argmin score == argmax acc.
//  - running per-row max (cross-lane shfl within the 16-lane group) gives conservative
//    threshold thr = runmax - tau/2; flagged (row,n) go to an LDS queue.
//  - queue batch-rescored exactly (sequential fp32 j-chain, (A-2m)+cse contract-off,
//    identical to the verified scalar kernel), merged lex-min (d, then k) == ascending
//    strict-< argmin. Winner's exact d feeds the same 256-leaf loss tree.
__global__ __launch_bounds__(256, 2) void vq_mfma(
        const float* __restrict__ in,
        const float* __restrict__ cb,
        float* __restrict__ ws,
        float* __restrict__ codes_f,
        float* __restrict__ out)
{
    __shared__ float csq_s[KCB];
    __shared__ float Atab[RPB];
    __shared__ float Ttab[RPB];
    __shared__ float dtab[RPB];
    __shared__ int   ktab[RPB];
    __shared__ int   qcnt[4];
    __shared__ int   ovfl;
    __shared__ int   qbuf[4][QCAP];
    __shared__ float dres[4][QCAP];

    const int tid  = threadIdx.x;
    const int lane = tid & 63;
    const int w    = tid >> 6;
    const int r    = lane & 15;
    const int g    = lane >> 4;
    const int wrow = w << 6;
    const size_t rowBase = (size_t)blockIdx.x * RPB;
    const float* csq = ws + 256;
    const unsigned short* cbh = (const unsigned short*)(ws + 2048);
    float* loss_acc = ws;

    for (int i = tid; i < KCB; i += 256) csq_s[i] = csq[i];
    dtab[tid] = 3.402823466e38f;
    ktab[tid] = 0;
    if (tid < 4) qcnt[tid] = 0;
    if (tid == 0) ovfl = 0;

    // ---- per-row A (exact pairwise-8 order), S1, tau/2 ----
    {
        const int rowl = wrow + lane;
        const float4* x4 = (const float4*)(in + (rowBase + rowl) * (size_t)DIM);
        float xv[64];
        #pragma unroll
        for (int j = 0; j < 16; ++j) {
            float4 v = x4[j];
            xv[j*4+0]=v.x; xv[j*4+1]=v.y; xv[j*4+2]=v.z; xv[j*4+3]=v.w;
        }
        float A;
        {
            #pragma clang fp contract(off)
            float racc[8];
            #pragma unroll
            for (int j = 0; j < 8; ++j) racc[j] = xv[j]*xv[j];
            #pragma unroll
            for (int t = 1; t < 8; ++t) {
                #pragma unroll
                for (int j = 0; j < 8; ++j) racc[j] += xv[8*t+j]*xv[8*t+j];
            }
            A = ((racc[0]+racc[1])+(racc[2]+racc[3]))
              + ((racc[4]+racc[5])+(racc[6]+racc[7]));
        }
        float S1 = 0.f;
        #pragma unroll
        for (int j = 0; j < 64; ++j) S1 += __builtin_fabsf(xv[j]);
        Atab[rowl] = A;
        // tau/2: certified |exact_d - approx_score| bound with >=2x margin
        Ttab[rowl] = 1.52587890625e-05f * S1
                   + 4.76837158203125e-07f * (A + 1.0f)
                   + 1e-5f;
    }

    // ---- A-fragments (bf16 hi of x), persist across the whole scan ----
    short8 af[4][2];
    #pragma unroll
    for (int mt = 0; mt < 4; ++mt)
        #pragma unroll
        for (int h = 0; h < 2; ++h) {
            const float4* f4 = (const float4*)(in + (rowBase + wrow + mt*16 + r) * (size_t)DIM
                                               + h*32 + g*8);
            float4 v0 = f4[0], v1 = f4[1];
            short8 a;
            a[0]=(short)f2bf(v0.x); a[1]=(short)f2bf(v0.y);
            a[2]=(short)f2bf(v0.z); a[3]=(short)f2bf(v0.w);
            a[4]=(short)f2bf(v1.x); a[5]=(short)f2bf(v1.y);
            a[6]=(short)f2bf(v1.z); a[7]=(short)f2bf(v1.w);
            af[mt][h] = a;
        }

    __syncthreads();

    float th_r[16];
    #pragma unroll
    for (int mt = 0; mt < 4; ++mt)
        #pragma unroll
        for (int rg = 0; rg < 4; ++rg)
            th_r[mt*4+rg] = Ttab[wrow + mt*16 + g*4 + rg];

    float rm[16];
    #pragma unroll
    for (int s = 0; s < 16; ++s) rm[s] = -3.402823466e38f;

    // ---- MFMA scan: 16 chunks of 64 entries ----
    #pragma unroll 1
    for (int nb = 0; nb < KCB; nb += 64) {
        short8 bf[4][2];
        #pragma unroll
        for (int nt = 0; nt < 4; ++nt)
            #pragma unroll
            for (int h = 0; h < 2; ++h)
                bf[nt][h] = *(const short8*)(cbh + ((nb + nt*16 + r) << 6) + h*32 + g*8);

        float csqh[4];
        #pragma unroll
        for (int nt = 0; nt < 4; ++nt) csqh[nt] = -0.5f * csq_s[nb + nt*16 + r];

        f32x4 acc[4][4];
        #pragma unroll
        for (int mt = 0; mt < 4; ++mt)
            #pragma unroll
            for (int nt = 0; nt < 4; ++nt) {
                f32x4 c; c[0]=csqh[nt]; c[1]=csqh[nt]; c[2]=csqh[nt]; c[3]=csqh[nt];
                acc[mt][nt] = c;
            }

        #pragma unroll
        for (int h = 0; h < 2; ++h)
            #pragma unroll
            for (int nt = 0; nt < 4; ++nt)
                #pragma unroll
                for (int mt = 0; mt < 4; ++mt)
                    acc[mt][nt] = __builtin_amdgcn_mfma_f32_16x16x32_bf16(
                        af[mt][h], bf[nt][h], acc[mt][nt], 0, 0, 0);

        // flag candidates vs running per-row max (conservative: thr <= final thr)
        #pragma unroll
        for (int mt = 0; mt < 4; ++mt)
            #pragma unroll
            for (int rg = 0; rg < 4; ++rg) {
                const int s = mt*4 + rg;
                float cm = fmaxf(fmaxf(acc[mt][0][rg], acc[mt][1][rg]),
                                 fmaxf(acc[mt][2][rg], acc[mt][3][rg]));
                cm = fmaxf(cm, __shfl_xor(cm, 1));
                cm = fmaxf(cm, __shfl_xor(cm, 2));
                cm = fmaxf(cm, __shfl_xor(cm, 4));
                cm = fmaxf(cm, __shfl_xor(cm, 8));
                rm[s] = fmaxf(rm[s], cm);
                const float thr = rm[s] - th_r[s];
                const bool f0 = acc[mt][0][rg] >= thr;
                const bool f1 = acc[mt][1][rg] >= thr;
                const bool f2 = acc[mt][2][rg] >= thr;
                const bool f3 = acc[mt][3][rg] >= thr;
                if (f0 | f1 | f2 | f3) {
                    const int rowblk = wrow + mt*16 + g*4 + rg;
                    #pragma unroll
                    for (int nt = 0; nt < 4; ++nt) {
                        const bool fl = (nt==0)?f0:(nt==1)?f1:(nt==2)?f2:f3;
                        if (fl) {
                            int qi = atomicAdd(&qcnt[w], 1);
                            if (qi < QCAP) qbuf[w][qi] = (rowblk << 10) | (nb + nt*16 + r);
                            else ovfl = 1;
                        }
                    }
                }
            }
    }

    // ---- batched exact rescore (64-wide rounds) ----
    const int cnt  = qcnt[w];
    const int cmax = cnt < QCAP ? cnt : QCAP;
    for (int base = 0; base < cmax; base += 64) {
        const int i = base + lane;
        if (i < cmax) {
            const int item = qbuf[w][i];
            const int rowblk = item >> 10;
            const int n = item & 1023;
            const float4* x4 = (const float4*)(in + (rowBase + rowblk) * (size_t)DIM);
            const float4* e4 = (const float4*)(cb + ((size_t)n << 6));
            float mm = 0.f;
            #pragma unroll
            for (int j = 0; j < 16; ++j) {
                float4 xq = x4[j], eq = e4[j];
                mm = __builtin_fmaf(xq.x, eq.x, mm);
                mm = __builtin_fmaf(xq.y, eq.y, mm);
                mm = __builtin_fmaf(xq.z, eq.z, mm);
                mm = __builtin_fmaf(xq.w, eq.w, mm);
            }
            float dd;
            {
                #pragma clang fp contract(off)
                dd = (Atab[rowblk] - 2.0f * mm) + csq_s[n];
            }
            dres[w][i] = dd;
        }
    }

    // ---- serial lex-min merge (lane 0; rows are wave-exclusive -> race-free) ----
    if (lane == 0) {
        for (int i = 0; i < cmax; ++i) {
            const int item = qbuf[w][i];
            const int rowblk = item >> 10;
            const int n = item & 1023;
            const float d = dres[w][i];
            const float od = dtab[rowblk];
            const int   ok = ktab[rowblk];
            if (d < od || (d == od && n < ok)) { dtab[rowblk] = d; ktab[rowblk] = n; }
        }
    }
    __syncthreads();

    // ---- overflow fallback: full exact scan per row (practically unreachable) ----
    if (ovfl) {
        const float* xr = in + (rowBase + tid) * (size_t)DIM;
        float dmin = 3.402823466e38f; int kmin = 0;
        for (int n = 0; n < KCB; ++n) {
            const float* eg = cb + ((size_t)n << 6);
            float mm = 0.f;
            for (int j = 0; j < 64; ++j) mm = __builtin_fmaf(xr[j], eg[j], mm);
            float dd;
            {
                #pragma clang fp contract(off)
                dd = (Atab[tid] - 2.0f * mm) + csq_s[n];
            }
            if (dd < dmin) { dmin = dd; kmin = n; }
        }
        dtab[tid] = dmin; ktab[tid] = kmin;
    }
    __syncthreads();

    codes_f[rowBase + tid] = (float)ktab[tid];

    // ---- fused straight-through write: st = x + (q - x) ----
    {
        const float4* gx = (const float4*)(in + rowBase * DIM);
        float4* gout = (float4*)(out + rowBase * DIM);
        #pragma unroll
        for (int i = 0; i < 16; ++i) {
            int idx = i * 256 + tid;
            int row = idx >> 4, cj = idx & 15;
            int code = ktab[row];
            float4 qv = *(const float4*)(cb + ((size_t)code << 6) + (cj << 2));
            float4 xv = gx[idx];
            float4 st;
            {
                #pragma clang fp contract(off)
                st.x = xv.x + (qv.x - xv.x);
                st.y = xv.y + (qv.y - xv.y);
                st.z = xv.z + (qv.z - xv.z);
                st.w = xv.w + (qv.w - xv.w);
            }
            gout[idx] = st;
        }
    }

    // ---- loss partial (identical 256-leaf tree) ----
    __syncthreads();
    #pragma unroll
    for (int s = 128; s > 0; s >>= 1) {
        if (tid < s) dtab[tid] += dtab[tid + s];
        __syncthreads();
    }
    if (tid == 0) atomicAdd(loss_acc, dtab[0]);
}

// ===================== fallback: R1 scalar kernel (used only if ws too small) ==========
#define OLD_SMEM_WORDS 20480
#define OLD_SMEM_BYTES (OLD_SMEM_WORDS * 4)

__global__ __launch_bounds__(512, 4) void vq_main_old(
        const float* __restrict__ in,
        const float* __restrict__ cb,
        const float* __restrict__ csq,
        float* __restrict__ codes_f,
        float* __restrict__ out,
        float* __restrict__ loss_acc)
{
    extern __shared__ float smem[];
    float* xs    = smem;
    float* dtab  = smem + 16384;
    int*   ktab  = (int*)(smem + 18432);

    const int tid  = threadIdx.x;
    const int lane = tid & 63;
    const int q    = __builtin_amdgcn_readfirstlane(tid >> 6);
    const size_t rowBase = (size_t)blockIdx.x * RPB;

    {
        const float4* gx = (const float4*)(in + rowBase * DIM);
        #pragma unroll
        for (int i = 0; i < 8; ++i) {
            int idx = i * 512 + tid;
            int row = idx >> 4, cj = idx & 15;
            float4 v = gx[idx];
            *(float4*)(xs + row * 64 + ((cj ^ (row & 15)) << 2)) = v;
        }
    }
    __syncthreads();

    float A[4];
    #pragma unroll
    for (int ri = 0; ri < 4; ++ri) {
        const int row = lane + (ri << 6);
        float xv[64];
        #pragma unroll
        for (int cj = 0; cj < 16; ++cj) {
            float4 v = *(const float4*)(xs + row * 64 + ((cj ^ (lane & 15)) << 2));
            xv[cj*4+0]=v.x; xv[cj*4+1]=v.y; xv[cj*4+2]=v.z; xv[cj*4+3]=v.w;
        }
        {
            #pragma clang fp contract(off)
            float racc[8];
            #pragma unroll
            for (int j = 0; j < 8; ++j) racc[j] = xv[j] * xv[j];
            #pragma unroll
            for (int t = 1; t < 8; ++t) {
                #pragma unroll
                for (int j = 0; j < 8; ++j) racc[j] += xv[8*t+j] * xv[8*t+j];
            }
            A[ri] = ((racc[0] + racc[1]) + (racc[2] + racc[3]))
                  + ((racc[4] + racc[5]) + (racc[6] + racc[7]));
        }
    }

    const float* cbq   = cb  + ((size_t)q << 13);
    const float* csq_q = csq + (q << 7);
    float dmin[4] = {3.402823466e38f, 3.402823466e38f, 3.402823466e38f, 3.402823466e38f};
    int   kmin[4] = {0, 0, 0, 0};
    const int xb = lane * 64;

    #pragma unroll 1
    for (int ke = 0; ke < 128; ke += 16) {
        float m[4][16];
        #pragma unroll
        for (int ri = 0; ri < 4; ++ri)
            #pragma unroll
            for (int e = 0; e < 16; ++e) m[ri][e] = 0.0f;

        #pragma unroll 1
        for (int jb = 0; jb < 64; jb += 4) {
            const int slot4 = ((jb >> 2) ^ (lane & 15)) << 2;
            float4 a0 = *(const float4*)(xs + xb +         slot4);
            float4 a1 = *(const float4*)(xs + xb +  4096 + slot4);
            float4 a2 = *(const float4*)(xs + xb +  8192 + slot4);
            float4 a3 = *(const float4*)(xs + xb + 12288 + slot4);
            #pragma unroll
            for (int e = 0; e < 16; ++e) {
                float4 ev = *(const float4*)(cbq + ((ke + e) << 6) + jb);
                m[0][e] = __builtin_fmaf(a0.x, ev.x, m[0][e]);
                m[0][e] = __builtin_fmaf(a0.y, ev.y, m[0][e]);
                m[0][e] = __builtin_fmaf(a0.z, ev.z, m[0][e]);
                m[0][e] = __builtin_fmaf(a0.w, ev.w, m[0][e]);
                m[1][e] = __builtin_fmaf(a1.x, ev.x, m[1][e]);
                m[1][e] = __builtin_fmaf(a1.y, ev.y, m[1][e]);
                m[1][e] = __builtin_fmaf(a1.z, ev.z, m[1][e]);
                m[1][e] = __builtin_fmaf(a1.w, ev.w, m[1][e]);
                m[2][e] = __builtin_fmaf(a2.x, ev.x, m[2][e]);
                m[2][e] = __builtin_fmaf(a2.y, ev.y, m[2][e]);
                m[2][e] = __builtin_fmaf(a2.z, ev.z, m[2][e]);
                m[2][e] = __builtin_fmaf(a2.w, ev.w, m[2][e]);
                m[3][e] = __builtin_fmaf(a3.x, ev.x, m[3][e]);
                m[3][e] = __builtin_fmaf(a3.y, ev.y, m[3][e]);
                m[3][e] = __builtin_fmaf(a3.z, ev.z, m[3][e]);
                m[3][e] = __builtin_fmaf(a3.w, ev.w, m[3][e]);
            }
        }

        #pragma unroll
        for (int e = 0; e < 16; ++e) {
            float cse = csq_q[ke + e];
            int gk = (q << 7) + ke + e;
            #pragma unroll
            for (int ri = 0; ri < 4; ++ri) {
                float d;
                {
                    #pragma clang fp contract(off)
                    d = (A[ri] - 2.0f * m[ri][e]) + cse;
                }
                if (d < dmin[ri]) { dmin[ri] = d; kmin[ri] = gk; }
            }
        }
    }

    #pragma unroll
    for (int ri = 0; ri < 4; ++ri) {
        int row = lane + (ri << 6);
        dtab[row * 8 + q] = dmin[ri];
        ktab[row * 8 + q] = kmin[ri];
    }
    __syncthreads();

    float db = 0.0f;
    if (tid < RPB) {
        db = dtab[tid * 8];
        int kb = ktab[tid * 8];
        #pragma unroll
        for (int qq = 1; qq < 8; ++qq) {
            float dq = dtab[tid * 8 + qq];
            int   kq = ktab[tid * 8 + qq];
            if (dq < db) { db = dq; kb = kq; }
        }
        ktab[tid * 8] = kb;
        codes_f[rowBase + tid] = (float)kb;
    }
    __syncthreads();

    {
        float4* gout = (float4*)(out + rowBase * DIM);
        #pragma unroll
        for (int i = 0; i < 8; ++i) {
            int idx = i * 512 + tid;
            int row = idx >> 4, cj = idx & 15;
            int code = ktab[row * 8];
            float4 qv = *(const float4*)(cb + ((size_t)code << 6) + (cj << 2));
            float4 xv = *(const float4*)(xs + row * 64 + ((cj ^ (row & 15)) << 2));
            float4 st;
            {
                #pragma clang fp contract(off)
                st.x = xv.x + (qv.x - xv.x);
                st.y = xv.y + (qv.y - xv.y);
                st.z = xv.z + (qv.z - xv.z);
                st.w = xv.w + (qv.w - xv.w);
            }
            gout[idx] = st;
        }
    }

    if (tid < RPB) dtab[tid] = db;
    __syncthreads();
    #pragma unroll
    for (int s = 128; s > 0; s >>= 1) {
        if (tid < s) dtab[tid] += dtab[tid + s];
        __syncthreads();
    }
    if (tid == 0) atomicAdd(loss_acc, dtab[0]);
}

__global__ void vq_final(const float* __restrict__ ws, float* __restrict__ loss_out) {
    loss_out[0] = 1.25f * ws[0] / 8388608.0f;
}

extern "C" void kernel_launch(void* const* d_in, const int* in_sizes, int n_in,
                              void* d_out, int out_size, void* d_ws, size_t ws_size,
                              hipStream_t stream) {
    const float* in = (const float*)d_in[0];   // (32,4096,64) fp32
    const float* cb = (const float*)d_in[1];   // (1024,64)    fp32
    float* out     = (float*)d_out;
    float* codes_f = out + 8388608;
    float* loss_p  = out + 8519680;
    float* ws      = (float*)d_ws;

    const int big = (ws_size >= (size_t)WS_NEED_BYTES) ? 1 : 0;

    vq_prep<<<4, 256, 0, stream>>>(cb, ws, big);
    if (big) {
        vq_mfma<<<512, 256, 0, stream>>>(in, cb, ws, codes_f, out);
    } else {
        hipFuncSetAttribute((const void*)vq_main_old,
                            hipFuncAttributeMaxDynamicSharedMemorySize, OLD_SMEM_BYTES);
        vq_main_old<<<512, 512, OLD_SMEM_BYTES, stream>>>(in, cb, ws + 256, codes_f, out, ws);
    }
    vq_final<<<1, 1, 0, stream>>>(ws, loss_p);
}

// Round 3
// 230.475 us; speedup vs baseline: 1.2669x; 1.1557x over previous
//
#include <hip/hip_runtime.h>

#define DIM   64
#define KCB   1024
#define RPB   256
#define QCAP  768      // per-wave (32 rows -> 24/row budget, same ratio as R2)

// ws layout (floats): ws[0] = loss acc; ws[256..1279] = csq[k];
//                     ws[2048..] = cb_hi bf16 [1024][64] (32768 float slots)
#define WS_NEED_BYTES ((2048 + 32768) * 4)

typedef __attribute__((ext_vector_type(8))) short short8;
typedef __attribute__((ext_vector_type(4))) float f32x4;

__device__ __forceinline__ unsigned short f2bf(float f) {
    union { float f; unsigned u; } v; v.f = f;
    unsigned u = v.u;
    return (unsigned short)((u + 0x7FFFu + ((u >> 16) & 1u)) >> 16);  // RNE
}

__global__ void vq_prep(const float* __restrict__ cb, float* __restrict__ ws, int do_bf) {
    int k = blockIdx.x * blockDim.x + threadIdx.x;
    if (k < KCB) {
        const float* e = cb + (k << 6);
        {
            #pragma clang fp contract(off)
            float racc[8];
            #pragma unroll
            for (int j = 0; j < 8; ++j) racc[j] = e[j] * e[j];
            #pragma unroll
            for (int t = 1; t < 8; ++t) {
                #pragma unroll
                for (int j = 0; j < 8; ++j) racc[j] += e[8 * t + j] * e[8 * t + j];
            }
            ws[256 + k] = ((racc[0] + racc[1]) + (racc[2] + racc[3]))
                        + ((racc[4] + racc[5]) + (racc[6] + racc[7]));
        }
        if (do_bf) {
            unsigned short* cbh = (unsigned short*)(ws + 2048);
            #pragma unroll
            for (int j = 0; j < 64; ++j) cbh[(k << 6) + j] = f2bf(e[j]);
        }
    }
    if (k == 0) ws[0] = 0.0f;
}

// Two-pass MFMA-filtered VQ (8 waves, 512 thr):
//  - wave w owns rows [w*32, w*32+32); A-frags persist in regs (mt in {0,1}).
//  - pass 1: MFMA scan, per-LANE running max only (no shfl/atomics/branches);
//    one cross-lane xor-reduce (r bits) at the end -> FINAL per-row threshold.
//  - pass 2: recompute identical MFMAs; flag acc >= thr via ballot-compacted
//    queue push (1 lane-0 atomic per non-empty group).
//  - exact rescore 64-wide; lex-min merge via 64-bit LDS atomicMin on
//    (d_bits<<32)|k  (d>0 -> bits monotone; ties -> smaller k), == ascending
//    strict-< argmin. Same certified tau, same exact fp32 chains as R2.
__global__ __launch_bounds__(512, 4) void vq_mfma(
        const float* __restrict__ in,
        const float* __restrict__ cb,
        float* __restrict__ ws,
        float* __restrict__ codes_f,
        float* __restrict__ out)
{
    __shared__ float csq_s[KCB];                 // 4 KB
    __shared__ float Atab[RPB];                  // 1 KB
    __shared__ float Ttab[RPB];                  // 1 KB
    __shared__ unsigned long long keytab[RPB];   // 2 KB
    __shared__ float dtab[RPB];                  // 1 KB
    __shared__ int   qcnt[8];
    __shared__ int   ovfl;
    __shared__ int   qbuf[8][QCAP];              // 24 KB

    const int tid  = threadIdx.x;
    const int lane = tid & 63;
    const int w    = tid >> 6;
    const int r    = lane & 15;
    const int g    = lane >> 4;
    const int wrow = w << 5;                     // 32 rows per wave
    const size_t rowBase = (size_t)blockIdx.x * RPB;
    const float* csq = ws + 256;
    const unsigned short* cbh = (const unsigned short*)(ws + 2048);
    float* loss_acc = ws;

    for (int i = tid; i < KCB; i += 512) csq_s[i] = csq[i];
    if (tid < RPB) keytab[tid] = 0xFFFFFFFFFFFFFFFFull;
    if (tid < 8) qcnt[tid] = 0;
    if (tid == 0) ovfl = 0;

    // ---- per-row A (exact pairwise-8 order), S1, tau (row = tid) ----
    if (tid < RPB) {
        const float4* x4 = (const float4*)(in + (rowBase + tid) * (size_t)DIM);
        float A, S1;
        {
            #pragma clang fp contract(off)
            float racc[8], sacc[8];
            float4 v0 = x4[0], v1 = x4[1];
            racc[0]=v0.x*v0.x; racc[1]=v0.y*v0.y; racc[2]=v0.z*v0.z; racc[3]=v0.w*v0.w;
            racc[4]=v1.x*v1.x; racc[5]=v1.y*v1.y; racc[6]=v1.z*v1.z; racc[7]=v1.w*v1.w;
            sacc[0]=__builtin_fabsf(v0.x); sacc[1]=__builtin_fabsf(v0.y);
            sacc[2]=__builtin_fabsf(v0.z); sacc[3]=__builtin_fabsf(v0.w);
            sacc[4]=__builtin_fabsf(v1.x); sacc[5]=__builtin_fabsf(v1.y);
            sacc[6]=__builtin_fabsf(v1.z); sacc[7]=__builtin_fabsf(v1.w);
            #pragma unroll
            for (int t = 1; t < 8; ++t) {
                float4 a = x4[2*t], b = x4[2*t+1];
                racc[0]+=a.x*a.x; racc[1]+=a.y*a.y; racc[2]+=a.z*a.z; racc[3]+=a.w*a.w;
                racc[4]+=b.x*b.x; racc[5]+=b.y*b.y; racc[6]+=b.z*b.z; racc[7]+=b.w*b.w;
                sacc[0]+=__builtin_fabsf(a.x); sacc[1]+=__builtin_fabsf(a.y);
                sacc[2]+=__builtin_fabsf(a.z); sacc[3]+=__builtin_fabsf(a.w);
                sacc[4]+=__builtin_fabsf(b.x); sacc[5]+=__builtin_fabsf(b.y);
                sacc[6]+=__builtin_fabsf(b.z); sacc[7]+=__builtin_fabsf(b.w);
            }
            A  = ((racc[0]+racc[1])+(racc[2]+racc[3]))
               + ((racc[4]+racc[5])+(racc[6]+racc[7]));
            S1 = ((sacc[0]+sacc[1])+(sacc[2]+sacc[3]))
               + ((sacc[4]+sacc[5])+(sacc[6]+sacc[7]));
        }
        Atab[tid] = A;
        Ttab[tid] = 1.52587890625e-05f * S1
                  + 4.76837158203125e-07f * (A + 1.0f)
                  + 1e-5f;                       // certified >= 2E, >=2x margin (R2-verified)
    }

    // ---- A-fragments (bf16 hi of x), persist across both passes ----
    short8 af[2][2];
    #pragma unroll
    for (int mt = 0; mt < 2; ++mt)
        #pragma unroll
        for (int h = 0; h < 2; ++h) {
            const float4* f4 = (const float4*)(in + (rowBase + wrow + mt*16 + r) * (size_t)DIM
                                               + h*32 + g*8);
            float4 v0 = f4[0], v1 = f4[1];
            short8 a;
            a[0]=(short)f2bf(v0.x); a[1]=(short)f2bf(v0.y);
            a[2]=(short)f2bf(v0.z); a[3]=(short)f2bf(v0.w);
            a[4]=(short)f2bf(v1.x); a[5]=(short)f2bf(v1.y);
            a[6]=(short)f2bf(v1.z); a[7]=(short)f2bf(v1.w);
            af[mt][h] = a;
        }

    __syncthreads();

    // ---- PASS 1: per-lane running max only ----
    float rm[8];
    #pragma unroll
    for (int s = 0; s < 8; ++s) rm[s] = -3.402823466e38f;

    #pragma unroll 1
    for (int nb = 0; nb < KCB; nb += 64) {
        short8 bf[4][2];
        #pragma unroll
        for (int nt = 0; nt < 4; ++nt)
            #pragma unroll
            for (int h = 0; h < 2; ++h)
                bf[nt][h] = *(const short8*)(cbh + ((nb + nt*16 + r) << 6) + h*32 + g*8);

        float csqh[4];
        #pragma unroll
        for (int nt = 0; nt < 4; ++nt) csqh[nt] = -0.5f * csq_s[nb + nt*16 + r];

        f32x4 acc[2][4];
        #pragma unroll
        for (int mt = 0; mt < 2; ++mt)
            #pragma unroll
            for (int nt = 0; nt < 4; ++nt) {
                f32x4 c; c[0]=csqh[nt]; c[1]=csqh[nt]; c[2]=csqh[nt]; c[3]=csqh[nt];
                acc[mt][nt] = c;
            }
        #pragma unroll
        for (int h = 0; h < 2; ++h)
            #pragma unroll
            for (int nt = 0; nt < 4; ++nt)
                #pragma unroll
                for (int mt = 0; mt < 2; ++mt)
                    acc[mt][nt] = __builtin_amdgcn_mfma_f32_16x16x32_bf16(
                        af[mt][h], bf[nt][h], acc[mt][nt], 0, 0, 0);

        #pragma unroll
        for (int mt = 0; mt < 2; ++mt)
            #pragma unroll
            for (int rg = 0; rg < 4; ++rg) {
                float cm = fmaxf(fmaxf(acc[mt][0][rg], acc[mt][1][rg]),
                                 fmaxf(acc[mt][2][rg], acc[mt][3][rg]));
                rm[mt*4+rg] = fmaxf(rm[mt*4+rg], cm);
            }
    }

    // ---- one cross-lane reduce (over r bits) -> final per-row threshold ----
    float thr[8];
    #pragma unroll
    for (int s = 0; s < 8; ++s) {
        float cm = rm[s];
        cm = fmaxf(cm, __shfl_xor(cm, 1));
        cm = fmaxf(cm, __shfl_xor(cm, 2));
        cm = fmaxf(cm, __shfl_xor(cm, 4));
        cm = fmaxf(cm, __shfl_xor(cm, 8));
        const int mt = s >> 2, rg = s & 3;
        thr[s] = cm - Ttab[wrow + mt*16 + g*4 + rg];
    }

    // ---- PASS 2: recompute (bit-identical) + ballot-compacted flagging ----
    #pragma unroll 1
    for (int nb = 0; nb < KCB; nb += 64) {
        short8 bf[4][2];
        #pragma unroll
        for (int nt = 0; nt < 4; ++nt)
            #pragma unroll
            for (int h = 0; h < 2; ++h)
                bf[nt][h] = *(const short8*)(cbh + ((nb + nt*16 + r) << 6) + h*32 + g*8);

        float csqh[4];
        #pragma unroll
        for (int nt = 0; nt < 4; ++nt) csqh[nt] = -0.5f * csq_s[nb + nt*16 + r];

        f32x4 acc[2][4];
        #pragma unroll
        for (int mt = 0; mt < 2; ++mt)
            #pragma unroll
            for (int nt = 0; nt < 4; ++nt) {
                f32x4 c; c[0]=csqh[nt]; c[1]=csqh[nt]; c[2]=csqh[nt]; c[3]=csqh[nt];
                acc[mt][nt] = c;
            }
        #pragma unroll
        for (int h = 0; h < 2; ++h)
            #pragma unroll
            for (int nt = 0; nt < 4; ++nt)
                #pragma unroll
                for (int mt = 0; mt < 2; ++mt)
                    acc[mt][nt] = __builtin_amdgcn_mfma_f32_16x16x32_bf16(
                        af[mt][h], bf[nt][h], acc[mt][nt], 0, 0, 0);

        #pragma unroll
        for (int mt = 0; mt < 2; ++mt)
            #pragma unroll
            for (int rg = 0; rg < 4; ++rg) {
                const float th = thr[mt*4+rg];
                const bool f0 = acc[mt][0][rg] >= th;
                const bool f1 = acc[mt][1][rg] >= th;
                const bool f2 = acc[mt][2][rg] >= th;
                const bool f3 = acc[mt][3][rg] >= th;
                if (__ballot(f0 | f1 | f2 | f3)) {       // uniform coarse skip
                    const int row = wrow + mt*16 + g*4 + rg;
                    #pragma unroll
                    for (int nt = 0; nt < 4; ++nt) {
                        const bool fl = (nt==0)?f0:(nt==1)?f1:(nt==2)?f2:f3;
                        unsigned long long m = __ballot(fl);
                        if (m) {
                            int base = 0;
                            if (lane == 0) base = atomicAdd(&qcnt[w], (int)__popcll(m));
                            base = __builtin_amdgcn_readfirstlane(base);
                            if (fl) {
                                int pos = base + (int)__popcll(m & ((1ull << lane) - 1ull));
                                if (pos < QCAP)
                                    qbuf[w][pos] = (row << 10) | (nb + nt*16 + r);
                                else ovfl = 1;
                            }
                        }
                    }
                }
            }
    }

    // ---- batched exact rescore + parallel lex-min merge ----
    const int cnt  = qcnt[w];
    const int cmax = cnt < QCAP ? cnt : QCAP;
    for (int base = 0; base < cmax; base += 64) {
        const int i = base + lane;
        if (i < cmax) {
            const int item = qbuf[w][i];
            const int row = item >> 10;
            const int n = item & 1023;
            const float4* x4 = (const float4*)(in + (rowBase + row) * (size_t)DIM);
            const float4* e4 = (const float4*)(cb + ((size_t)n << 6));
            float mm = 0.f;
            #pragma unroll
            for (int j = 0; j < 16; ++j) {
                float4 xq = x4[j], eq = e4[j];
                mm = __builtin_fmaf(xq.x, eq.x, mm);
                mm = __builtin_fmaf(xq.y, eq.y, mm);
                mm = __builtin_fmaf(xq.z, eq.z, mm);
                mm = __builtin_fmaf(xq.w, eq.w, mm);
            }
            float dd;
            {
                #pragma clang fp contract(off)
                dd = (Atab[row] - 2.0f * mm) + csq_s[n];
            }
            unsigned long long key =
                ((unsigned long long)__float_as_uint(dd) << 32) | (unsigned)n;
            atomicMin(&keytab[row], key);
        }
    }
    __syncthreads();

    // ---- per-row result, overflow fallback, code publish ----
    if (tid < RPB) {
        unsigned long long kk = keytab[tid];
        int   kb = (int)(kk & 1023u);
        float db = __uint_as_float((unsigned)(kk >> 32));
        if (ovfl) {   // practically unreachable; exact full scan
            const float* xr = in + (rowBase + tid) * (size_t)DIM;
            float dmin = 3.402823466e38f; int kmin = 0;
            for (int n = 0; n < KCB; ++n) {
                const float* eg = cb + ((size_t)n << 6);
                float mmv = 0.f;
                for (int j = 0; j < 64; ++j) mmv = __builtin_fmaf(xr[j], eg[j], mmv);
                float ddv;
                {
                    #pragma clang fp contract(off)
                    ddv = (Atab[tid] - 2.0f * mmv) + csq_s[n];
                }
                if (ddv < dmin) { dmin = ddv; kmin = n; }
            }
            db = dmin; kb = kmin;
        }
        dtab[tid] = db;
        codes_f[rowBase + tid] = (float)kb;
        keytab[tid] = (unsigned long long)(unsigned)kb;   // publish code for ST pass
    }
    __syncthreads();

    // ---- fused straight-through write: st = x + (q - x) ----
    {
        const float4* gx = (const float4*)(in + rowBase * DIM);
        float4* gout = (float4*)(out + rowBase * DIM);
        #pragma unroll
        for (int i = 0; i < 8; ++i) {
            int idx = i * 512 + tid;
            int row = idx >> 4, cj = idx & 15;
            int code = (int)keytab[row];
            float4 qv = *(const float4*)(cb + ((size_t)code << 6) + (cj << 2));
            float4 xv = gx[idx];
            float4 st;
            {
                #pragma clang fp contract(off)
                st.x = xv.x + (qv.x - xv.x);
                st.y = xv.y + (qv.y - xv.y);
                st.z = xv.z + (qv.z - xv.z);
                st.w = xv.w + (qv.w - xv.w);
            }
            gout[idx] = st;
        }
    }

    // ---- loss partial (identical 256-leaf tree) ----
    __syncthreads();
    #pragma unroll
    for (int s = 128; s > 0; s >>= 1) {
        if (tid < s) dtab[tid] += dtab[tid + s];
        __syncthreads();
    }
    if (tid == 0) atomicAdd(loss_acc, dtab[0]);
}

// ===================== fallback: R1 scalar kernel (used only if ws too small) ==========
#define OLD_SMEM_WORDS 20480
#define OLD_SMEM_BYTES (OLD_SMEM_WORDS * 4)

__global__ __launch_bounds__(512, 4) void vq_main_old(
        const float* __restrict__ in,
        const float* __restrict__ cb,
        const float* __restrict__ csq,
        float* __restrict__ codes_f,
        float* __restrict__ out,
        float* __restrict__ loss_acc)
{
    extern __shared__ float smem[];
    float* xs    = smem;
    float* dtab  = smem + 16384;
    int*   ktab  = (int*)(smem + 18432);

    const int tid  = threadIdx.x;
    const int lane = tid & 63;
    const int q    = __builtin_amdgcn_readfirstlane(tid >> 6);
    const size_t rowBase = (size_t)blockIdx.x * RPB;

    {
        const float4* gx = (const float4*)(in + rowBase * DIM);
        #pragma unroll
        for (int i = 0; i < 8; ++i) {
            int idx = i * 512 + tid;
            int row = idx >> 4, cj = idx & 15;
            float4 v = gx[idx];
            *(float4*)(xs + row * 64 + ((cj ^ (row & 15)) << 2)) = v;
        }
    }
    __syncthreads();

    float A[4];
    #pragma unroll
    for (int ri = 0; ri < 4; ++ri) {
        const int row = lane + (ri << 6);
        float xv[64];
        #pragma unroll
        for (int cj = 0; cj < 16; ++cj) {
            float4 v = *(const float4*)(xs + row * 64 + ((cj ^ (lane & 15)) << 2));
            xv[cj*4+0]=v.x; xv[cj*4+1]=v.y; xv[cj*4+2]=v.z; xv[cj*4+3]=v.w;
        }
        {
            #pragma clang fp contract(off)
            float racc[8];
            #pragma unroll
            for (int j = 0; j < 8; ++j) racc[j] = xv[j] * xv[j];
            #pragma unroll
            for (int t = 1; t < 8; ++t) {
                #pragma unroll
                for (int j = 0; j < 8; ++j) racc[j] += xv[8*t+j] * xv[8*t+j];
            }
            A[ri] = ((racc[0] + racc[1]) + (racc[2] + racc[3]))
                  + ((racc[4] + racc[5]) + (racc[6] + racc[7]));
        }
    }

    const float* cbq   = cb  + ((size_t)q << 13);
    const float* csq_q = csq + (q << 7);
    float dmin[4] = {3.402823466e38f, 3.402823466e38f, 3.402823466e38f, 3.402823466e38f};
    int   kmin[4] = {0, 0, 0, 0};
    const int xb = lane * 64;

    #pragma unroll 1
    for (int ke = 0; ke < 128; ke += 16) {
        float m[4][16];
        #pragma unroll
        for (int ri = 0; ri < 4; ++ri)
            #pragma unroll
            for (int e = 0; e < 16; ++e) m[ri][e] = 0.0f;

        #pragma unroll 1
        for (int jb = 0; jb < 64; jb += 4) {
            const int slot4 = ((jb >> 2) ^ (lane & 15)) << 2;
            float4 a0 = *(const float4*)(xs + xb +         slot4);
            float4 a1 = *(const float4*)(xs + xb +  4096 + slot4);
            float4 a2 = *(const float4*)(xs + xb +  8192 + slot4);
            float4 a3 = *(const float4*)(xs + xb + 12288 + slot4);
            #pragma unroll
            for (int e = 0; e < 16; ++e) {
                float4 ev = *(const float4*)(cbq + ((ke + e) << 6) + jb);
                m[0][e] = __builtin_fmaf(a0.x, ev.x, m[0][e]);
                m[0][e] = __builtin_fmaf(a0.y, ev.y, m[0][e]);
                m[0][e] = __builtin_fmaf(a0.z, ev.z, m[0][e]);
                m[0][e] = __builtin_fmaf(a0.w, ev.w, m[0][e]);
                m[1][e] = __builtin_fmaf(a1.x, ev.x, m[1][e]);
                m[1][e] = __builtin_fmaf(a1.y, ev.y, m[1][e]);
                m[1][e] = __builtin_fmaf(a1.z, ev.z, m[1][e]);
                m[1][e] = __builtin_fmaf(a1.w, ev.w, m[1][e]);
                m[2][e] = __builtin_fmaf(a2.x, ev.x, m[2][e]);
                m[2][e] = __builtin_fmaf(a2.y, ev.y, m[2][e]);
                m[2][e] = __builtin_fmaf(a2.z, ev.z, m[2][e]);
                m[2][e] = __builtin_fmaf(a2.w, ev.w, m[2][e]);
                m[3][e] = __builtin_fmaf(a3.x, ev.x, m[3][e]);
                m[3][e] = __builtin_fmaf(a3.y, ev.y, m[3][e]);
                m[3][e] = __builtin_fmaf(a3.z, ev.z, m[3][e]);
                m[3][e] = __builtin_fmaf(a3.w, ev.w, m[3][e]);
            }
        }

        #pragma unroll
        for (int e = 0; e < 16; ++e) {
            float cse = csq_q[ke + e];
            int gk = (q << 7) + ke + e;
            #pragma unroll
            for (int ri = 0; ri < 4; ++ri) {
                float d;
                {
                    #pragma clang fp contract(off)
                    d = (A[ri] - 2.0f * m[ri][e]) + cse;
                }
                if (d < dmin[ri]) { dmin[ri] = d; kmin[ri] = gk; }
            }
        }
    }

    #pragma unroll
    for (int ri = 0; ri < 4; ++ri) {
        int row = lane + (ri << 6);
        dtab[row * 8 + q] = dmin[ri];
        ktab[row * 8 + q] = kmin[ri];
    }
    __syncthreads();

    float db = 0.0f;
    if (tid < RPB) {
        db = dtab[tid * 8];
        int kb = ktab[tid * 8];
        #pragma unroll
        for (int qq = 1; qq < 8; ++qq) {
            float dq = dtab[tid * 8 + qq];
            int   kq = ktab[tid * 8 + qq];
            if (dq < db) { db = dq; kb = kq; }
        }
        ktab[tid * 8] = kb;
        codes_f[rowBase + tid] = (float)kb;
    }
    __syncthreads();

    {
        float4* gout = (float4*)(out + rowBase * DIM);
        #pragma unroll
        for (int i = 0; i < 8; ++i) {
            int idx = i * 512 + tid;
            int row = idx >> 4, cj = idx & 15;
            int code = ktab[row * 8];
            float4 qv = *(const float4*)(cb + ((size_t)code << 6) + (cj << 2));
            float4 xv = *(const float4*)(xs + row * 64 + ((cj ^ (row & 15)) << 2));
            float4 st;
            {
                #pragma clang fp contract(off)
                st.x = xv.x + (qv.x - xv.x);
                st.y = xv.y + (qv.y - xv.y);
                st.z = xv.z + (qv.z - xv.z);
                st.w = xv.w + (qv.w - xv.w);
            }
            gout[idx] = st;
        }
    }

    if (tid < RPB) dtab[tid] = db;
    __syncthreads();
    #pragma unroll
    for (int s = 128; s > 0; s >>= 1) {
        if (tid < s) dtab[tid] += dtab[tid + s];
        __syncthreads();
    }
    if (tid == 0) atomicAdd(loss_acc, dtab[0]);
}

__global__ void vq_final(const float* __restrict__ ws, float* __restrict__ loss_out) {
    loss_out[0] = 1.25f * ws[0] / 8388608.0f;
}

extern "C" void kernel_launch(void* const* d_in, const int* in_sizes, int n_in,
                              void* d_out, int out_size, void* d_ws, size_t ws_size,
                              hipStream_t stream) {
    const float* in = (const float*)d_in[0];   // (32,4096,64) fp32
    const float* cb = (const float*)d_in[1];   // (1024,64)    fp32
    float* out     = (float*)d_out;
    float* codes_f = out + 8388608;
    float* loss_p  = out + 8519680;
    float* ws      = (float*)d_ws;

    const int big = (ws_size >= (size_t)WS_NEED_BYTES) ? 1 : 0;

    vq_prep<<<4, 256, 0, stream>>>(cb, ws, big);
    if (big) {
        vq_mfma<<<512, 512, 0, stream>>>(in, cb, ws, codes_f, out);
    } else {
        hipFuncSetAttribute((const void*)vq_main_old,
                            hipFuncAttributeMaxDynamicSharedMemorySize, OLD_SMEM_BYTES);
        vq_main_old<<<512, 512, OLD_SMEM_BYTES, stream>>>(in, cb, ws + 256, codes_f, out, ws);
    }
    vq_final<<<1, 1, 0, stream>>>(ws, loss_p);
}